// Round 1
// baseline (5647.960 us; speedup 1.0000x reference)
//
#include <hip/hip_runtime.h>
#include <hip/hip_bf16.h>
#include <cstdint>
#include <cstddef>

#define NROWS 262144
#define EMB 256
#define NB 512
#define SLOPE 0.01f

// ---------------- init workspace accumulators ----------------
__global__ __launch_bounds__(256) void k_init(unsigned* segu, float* denom, float* xg) {
    int i = blockIdx.x * 256 + threadIdx.x;
    if (i < NB) { segu[i] = 0u; denom[i] = 0.f; }
    if (i < NB * EMB) xg[i] = 0.f;
}

// ---------------- gate[i] = x[i,:] . W_mask + b_mask ----------------
// one wave per row; lane holds 4 contiguous elements
__global__ __launch_bounds__(256) void k_gate(const float* __restrict__ x,
                                              const float* __restrict__ Wm,
                                              const float* __restrict__ bm,
                                              float* __restrict__ gate) {
    int lane = threadIdx.x & 63;
    int wave = threadIdx.x >> 6;
    int row  = blockIdx.x * 4 + wave;
    const float4 xv = *reinterpret_cast<const float4*>(x + (size_t)row * EMB + lane * 4);
    const float4 wv = *reinterpret_cast<const float4*>(Wm + lane * 4);
    float s = xv.x * wv.x + xv.y * wv.y + xv.z * wv.z + xv.w * wv.w;
#pragma unroll
    for (int off = 32; off > 0; off >>= 1) s += __shfl_down(s, off, 64);
    if (lane == 0) gate[row] = s + bm[0];
}

// ---------------- segment max via monotone-uint atomicMax ----------------
__global__ __launch_bounds__(256) void k_segmax(const float* __restrict__ gate,
                                                const int* __restrict__ bind,
                                                unsigned* __restrict__ segu) {
    int i = blockIdx.x * 256 + threadIdx.x;
    unsigned bits = __float_as_uint(gate[i]);
    unsigned enc  = (bits & 0x80000000u) ? ~bits : (bits | 0x80000000u);
    atomicMax(&segu[bind[i]], enc);
}

// ---------------- e = exp(gate - segmax); denom = segment_sum(e) ----------------
// overwrites gate with e in-place
__global__ __launch_bounds__(256) void k_expsum(float* __restrict__ gate,
                                                const int* __restrict__ bind,
                                                const unsigned* __restrict__ segu,
                                                float* __restrict__ denom) {
    int i = blockIdx.x * 256 + threadIdx.x;
    int b = bind[i];
    unsigned u = segu[b];
    float m = 0.f;
    if (u) {  // u==0 means empty segment (-inf -> 0 per reference isfinite guard)
        unsigned bb = (u & 0x80000000u) ? (u ^ 0x80000000u) : ~u;
        m = __uint_as_float(bb);
    }
    float ev = expf(gate[i] - m);
    gate[i] = ev;
    atomicAdd(&denom[b], ev);
}

// ---------------- feat GEMM + leaky_relu + weight + segmented reduce ----------------
// tile: 128 rows x 128 cols, 256 threads, 8x8 micro-tile per thread.
// LDS layouts are k-inner ([row][36] / [col][36]) so compute reads are
// float4 with <=2-way bank aliasing (free on CDNA4).
__global__ __launch_bounds__(256) void k_feat(const float* __restrict__ x,
                                              const float* __restrict__ Wf,
                                              const float* __restrict__ bfeat,
                                              const float* __restrict__ e,
                                              const float* __restrict__ denom,
                                              const int* __restrict__ bind,
                                              float* __restrict__ xg) {
    __shared__ union SM {
        struct { float xk[128][36]; float wt[128][36]; } s;  // staging (36.9 KB)
        float red[128][128];                                  // epilogue (64 KB)
    } sm;
    __shared__ int   seg_s[128];
    __shared__ float w_s[128];

    const int t  = threadIdx.x;
    const int r0 = blockIdx.x * 128;
    const int cb = blockIdx.y * 128;

    if (t < 128) {
        int row = r0 + t;
        int b   = bind[row];
        seg_s[t] = b;
        w_s[t]   = e[row] / fmaxf(denom[b], 1e-16f);
    }

    const int tx = t & 15, ty = t >> 4;
    float acc[8][8];
#pragma unroll
    for (int i = 0; i < 8; i++)
#pragma unroll
        for (int j = 0; j < 8; j++) acc[i][j] = 0.f;

    for (int kt = 0; kt < EMB; kt += 32) {
        // stage x tile: 128 rows x 32 k, transposed-to-[row][k] (already row-major)
#pragma unroll
        for (int q = 0; q < 4; q++) {
            int fid = q * 256 + t;
            int row = fid >> 3, k4 = fid & 7;
            *reinterpret_cast<float4*>(&sm.s.xk[row][k4 * 4]) =
                *reinterpret_cast<const float4*>(x + (size_t)(r0 + row) * EMB + kt + k4 * 4);
        }
        // stage W_feat tile transposed: wt[col][k]
#pragma unroll
        for (int q = 0; q < 4; q++) {
            int fid = q * 256 + t;
            int k = fid >> 5, c4 = fid & 31;
            float4 v = *reinterpret_cast<const float4*>(Wf + (size_t)(kt + k) * EMB + cb + c4 * 4);
            sm.s.wt[c4 * 4 + 0][k] = v.x;
            sm.s.wt[c4 * 4 + 1][k] = v.y;
            sm.s.wt[c4 * 4 + 2][k] = v.z;
            sm.s.wt[c4 * 4 + 3][k] = v.w;
        }
        __syncthreads();
#pragma unroll
        for (int kk = 0; kk < 32; kk += 4) {
            float4 xa[8], wb[8];
#pragma unroll
            for (int i = 0; i < 8; i++)
                xa[i] = *reinterpret_cast<const float4*>(&sm.s.xk[ty + 16 * i][kk]);
#pragma unroll
            for (int j = 0; j < 8; j++)
                wb[j] = *reinterpret_cast<const float4*>(&sm.s.wt[tx + 16 * j][kk]);
#pragma unroll
            for (int i = 0; i < 8; i++)
#pragma unroll
                for (int j = 0; j < 8; j++)
                    acc[i][j] += xa[i].x * wb[j].x + xa[i].y * wb[j].y +
                                 xa[i].z * wb[j].z + xa[i].w * wb[j].w;
        }
        __syncthreads();
    }

    // epilogue: bias -> leaky_relu -> * softmax weight -> LDS
#pragma unroll
    for (int i = 0; i < 8; i++) {
        int r = ty + 16 * i;
        float wr = w_s[r];
#pragma unroll
        for (int j = 0; j < 8; j++) {
            int c = tx + 16 * j;
            float v = acc[i][j] + bfeat[cb + c];
            v = (v >= 0.f) ? v : SLOPE * v;
            sm.red[r][c] = v * wr;
        }
    }
    __syncthreads();

    // segmented column reduction over the 128 sorted rows; ~2 atomics/(col,half)
    {
        int c = t & 127, hh = t >> 7;
        int rbeg = hh * 64;
        int cur = seg_s[rbeg];
        float s = 0.f;
        for (int r = rbeg; r < rbeg + 64; r++) {
            int sg = seg_s[r];
            if (sg != cur) {
                atomicAdd(&xg[(size_t)cur * EMB + cb + c], s);
                s = 0.f;
                cur = sg;
            }
            s += sm.red[r][c];
        }
        atomicAdd(&xg[(size_t)cur * EMB + cb + c], s);
    }
}

// ---------------- out = leaky_relu([xg, xg_prev] @ W_t + b_t) + xg_prev ----------------
__global__ __launch_bounds__(256) void k_out(const float* __restrict__ xg,
                                             const float* __restrict__ xgp,
                                             const float* __restrict__ Wt,
                                             const float* __restrict__ bt,
                                             float* __restrict__ out) {
    __shared__ float h[8][512];
    int c  = threadIdx.x;
    int b0 = blockIdx.x * 8;
#pragma unroll
    for (int q = 0; q < 16; q++) {
        int idx = q * 256 + c;
        int r = idx >> 9, k = idx & 511;
        h[r][k] = (k < EMB) ? xg[(size_t)(b0 + r) * EMB + k]
                            : xgp[(size_t)(b0 + r) * EMB + (k - EMB)];
    }
    __syncthreads();
    float acc[8] = {0.f, 0.f, 0.f, 0.f, 0.f, 0.f, 0.f, 0.f};
    for (int k = 0; k < 2 * EMB; k++) {
        float wv = Wt[(size_t)k * EMB + c];
#pragma unroll
        for (int r = 0; r < 8; r++) acc[r] += h[r][k] * wv;
    }
#pragma unroll
    for (int r = 0; r < 8; r++) {
        float v = acc[r] + bt[c];
        v = (v >= 0.f) ? v : SLOPE * v;
        out[(size_t)(b0 + r) * EMB + c] = v + xgp[(size_t)(b0 + r) * EMB + c];
    }
}

extern "C" void kernel_launch(void* const* d_in, const int* in_sizes, int n_in,
                              void* d_out, int out_size, void* d_ws, size_t ws_size,
                              hipStream_t stream) {
    const float* xgp  = (const float*)d_in[0];
    const float* x    = (const float*)d_in[1];
    const int*   bind = (const int*)d_in[2];
    const float* Wm   = (const float*)d_in[3];
    const float* bm   = (const float*)d_in[4];
    const float* Wf   = (const float*)d_in[5];
    const float* bf   = (const float*)d_in[6];
    const float* Wt   = (const float*)d_in[7];
    const float* bt   = (const float*)d_in[8];
    float* out = (float*)d_out;

    char* ws = (char*)d_ws;
    float*    gate  = (float*)ws;                                   // N f32, becomes e
    unsigned* segu  = (unsigned*)(ws + (size_t)NROWS * 4);          // NB u32
    float*    denom = (float*)(ws + (size_t)NROWS * 4 + NB * 4);    // NB f32
    float*    xg    = (float*)(ws + (size_t)NROWS * 4 + NB * 8);    // NB*EMB f32

    hipLaunchKernelGGL(k_init,   dim3((NB * EMB + 255) / 256), dim3(256), 0, stream, segu, denom, xg);
    hipLaunchKernelGGL(k_gate,   dim3(NROWS / 4),   dim3(256), 0, stream, x, Wm, bm, gate);
    hipLaunchKernelGGL(k_segmax, dim3(NROWS / 256), dim3(256), 0, stream, gate, bind, segu);
    hipLaunchKernelGGL(k_expsum, dim3(NROWS / 256), dim3(256), 0, stream, gate, bind, segu, denom);
    hipLaunchKernelGGL(k_feat,   dim3(NROWS / 128, 2), dim3(256), 0, stream, x, Wf, bf, gate, denom, bind, xg);
    hipLaunchKernelGGL(k_out,    dim3(NB / 8),      dim3(256), 0, stream, xg, xgp, Wt, bt, out);
}

// Round 2
// 661.695 us; speedup vs baseline: 8.5356x; 8.5356x over previous
//
#include <hip/hip_runtime.h>
#include <cstdint>
#include <cstddef>

#define NROWS 262144
#define EMB 256
#define NB 512
#define SLOPE 0.01f

typedef __attribute__((ext_vector_type(8))) short short8;
typedef __attribute__((ext_vector_type(4))) float f32x4;

__device__ __forceinline__ unsigned short f2bf(float f) {
    unsigned u = __float_as_uint(f);
    u += 0x7FFFu + ((u >> 16) & 1u);
    return (unsigned short)(u >> 16);
}

// ---------- prep: transpose W_feat -> bf16 Wt[col][k], zero denom & xg ----------
__global__ __launch_bounds__(256) void k_prep(const float* __restrict__ Wf,
                                              unsigned short* __restrict__ Wt,
                                              float* __restrict__ denom,
                                              float* __restrict__ xg) {
    int b = blockIdx.x, t = threadIdx.x;
    if (b < 256) {
        float v = Wf[(size_t)b * EMB + t];   // W_feat[k=b][col=t]
        Wt[(size_t)t * EMB + b] = f2bf(v);   // Wt[col][k]
        xg[(size_t)b * 512 + t] = 0.f;
        xg[(size_t)b * 512 + 256 + t] = 0.f;
    } else if (b == 256) {
        denom[t] = 0.f;
    } else {
        denom[256 + t] = 0.f;
    }
}

// ---------- fused: gate + exp + bf16 MFMA feat GEMM + weighted segment reduce ----------
// 256 threads (4 waves). Tile: 64 rows x 256 cols, BK=32 (one MFMA K-step per iter).
// Wave w: wr=w>>1 (row half, 32 rows), wc=w&1 (col half, 128 cols); 2x8 fragments.
__global__ __launch_bounds__(256) void k_fused(const float* __restrict__ x,
                                               const unsigned short* __restrict__ Wt,
                                               const float* __restrict__ wm,
                                               const float* __restrict__ bm,
                                               const float* __restrict__ bfeat,
                                               const int* __restrict__ bind,
                                               float* __restrict__ denom,
                                               float* __restrict__ xg) {
    __shared__ unsigned short xa_s[64][40];    // 64 rows x 32 k bf16, pad 8
    __shared__ unsigned short wt_s[256][40];   // 256 cols x 32 k bf16, pad 8
    __shared__ float wm_s[256];
    __shared__ float gp_s[64][4];
    __shared__ float w_s[64];
    __shared__ int   seg_s[64];
    __shared__ int   segid_s[4];
    __shared__ int   uni_s[4];

    const int t  = threadIdx.x;
    const int r0 = blockIdx.x * 64;

    wm_s[t] = wm[t];
    if (t < 64) seg_s[t] = bind[r0 + t];
    __syncthreads();
    if (t < 4) {
        int s0 = seg_s[t * 16], ok = 1;
#pragma unroll
        for (int i = 1; i < 16; i++) ok &= (seg_s[t * 16 + i] == s0);
        segid_s[t] = s0;
        uni_s[t]   = ok;
    }

    const int lane = t & 63;
    const int w    = t >> 6;
    const int wr   = w >> 1, wc = w & 1;
    const int fr   = lane & 15;
    const int fk   = (lane >> 4) * 8;

    f32x4 acc[2][8];
#pragma unroll
    for (int m = 0; m < 2; m++)
#pragma unroll
        for (int n = 0; n < 8; n++) acc[m][n] = (f32x4){0.f, 0.f, 0.f, 0.f};

    const int srow = t & 63, sq = t >> 6;               // x staging: row, k-quarter
    const float* xp = x + (size_t)(r0 + srow) * EMB + sq * 8;
    const unsigned short* wrow = Wt + (size_t)t * EMB;  // W staging: col t
    float gp = 0.f;

    for (int kt = 0; kt < EMB; kt += 32) {
        // ---- global loads (issue early) ----
        float4 xv0 = *reinterpret_cast<const float4*>(xp + kt);
        float4 xv1 = *reinterpret_cast<const float4*>(xp + kt + 4);
        int4 wv0 = *reinterpret_cast<const int4*>(wrow + kt);
        int4 wv1 = *reinterpret_cast<const int4*>(wrow + kt + 8);
        int4 wv2 = *reinterpret_cast<const int4*>(wrow + kt + 16);
        int4 wv3 = *reinterpret_cast<const int4*>(wrow + kt + 24);
        // ---- gate partial (fp32) ----
        const float4 wa = *reinterpret_cast<const float4*>(&wm_s[kt + sq * 8]);
        const float4 wb = *reinterpret_cast<const float4*>(&wm_s[kt + sq * 8 + 4]);
        gp += xv0.x * wa.x + xv0.y * wa.y + xv0.z * wa.z + xv0.w * wa.w
            + xv1.x * wb.x + xv1.y * wb.y + xv1.z * wb.z + xv1.w * wb.w;

        __syncthreads();  // previous iter's frag reads done
        short8 xs;
        xs[0] = (short)f2bf(xv0.x); xs[1] = (short)f2bf(xv0.y);
        xs[2] = (short)f2bf(xv0.z); xs[3] = (short)f2bf(xv0.w);
        xs[4] = (short)f2bf(xv1.x); xs[5] = (short)f2bf(xv1.y);
        xs[6] = (short)f2bf(xv1.z); xs[7] = (short)f2bf(xv1.w);
        *reinterpret_cast<short8*>(&xa_s[srow][sq * 8]) = xs;
        *reinterpret_cast<int4*>(&wt_s[t][0])  = wv0;
        *reinterpret_cast<int4*>(&wt_s[t][8])  = wv1;
        *reinterpret_cast<int4*>(&wt_s[t][16]) = wv2;
        *reinterpret_cast<int4*>(&wt_s[t][24]) = wv3;
        __syncthreads();  // tile ready

        // ---- fragments + MFMA ----
        short8 af0 = *reinterpret_cast<const short8*>(&xa_s[wr * 32 + fr][fk]);
        short8 af1 = *reinterpret_cast<const short8*>(&xa_s[wr * 32 + 16 + fr][fk]);
        short8 bfr[8];
#pragma unroll
        for (int n = 0; n < 8; n++)
            bfr[n] = *reinterpret_cast<const short8*>(&wt_s[wc * 128 + n * 16 + fr][fk]);
#pragma unroll
        for (int n = 0; n < 8; n++) {
            acc[0][n] = __builtin_amdgcn_mfma_f32_16x16x32_bf16(af0, bfr[n], acc[0][n], 0, 0, 0);
            acc[1][n] = __builtin_amdgcn_mfma_f32_16x16x32_bf16(af1, bfr[n], acc[1][n], 0, 0, 0);
        }
    }

    // ---- gate -> e, denom ----
    gp_s[srow][sq] = gp;
    __syncthreads();
    if (t < 64) {
        float g = gp_s[t][0] + gp_s[t][1] + gp_s[t][2] + gp_s[t][3] + bm[0];
        float e = expf(g);
        w_s[t] = e;
        atomicAdd(&denom[seg_s[t]], e);
    }
    __syncthreads();

    // ---- epilogue: bias -> leaky -> *e -> segmented reduce -> atomics ----
#pragma unroll
    for (int m = 0; m < 2; m++) {
        const int g    = wr * 2 + m;
        const int rowb = wr * 32 + m * 16;
        const int uni  = uni_s[g];
        const int sid  = segid_s[g];
#pragma unroll
        for (int n = 0; n < 8; n++) {
            const int col = wc * 128 + n * 16 + fr;
            const float bia = bfeat[col];
            float vr[4];
#pragma unroll
            for (int r = 0; r < 4; r++) {
                const int row = rowb + (lane >> 4) * 4 + r;
                float v = acc[m][n][r] + bia;
                v = (v >= 0.f) ? v : SLOPE * v;
                vr[r] = v * w_s[row];
            }
            if (uni) {
                float s = vr[0] + vr[1] + vr[2] + vr[3];
                s += __shfl_xor(s, 16, 64);
                s += __shfl_xor(s, 32, 64);
                if ((lane >> 4) == 0)
                    atomicAdd(&xg[(size_t)sid * EMB + col], s);
            } else {
#pragma unroll
                for (int r = 0; r < 4; r++) {
                    const int row = rowb + (lane >> 4) * 4 + r;
                    atomicAdd(&xg[(size_t)seg_s[row] * EMB + col], vr[r]);
                }
            }
        }
    }
}

// ---------- out = leaky_relu([xg/denom, xg_prev] @ W_t + b_t) + xg_prev ----------
__global__ __launch_bounds__(256) void k_out(const float* __restrict__ xg,
                                             const float* __restrict__ denom,
                                             const float* __restrict__ xgp,
                                             const float* __restrict__ Wtr,
                                             const float* __restrict__ bt,
                                             float* __restrict__ out) {
    __shared__ float h[8][512];
    const int c  = threadIdx.x;
    const int b0 = blockIdx.x * 8;
    float rden[8];
#pragma unroll
    for (int r = 0; r < 8; r++) rden[r] = 1.f / fmaxf(denom[b0 + r], 1e-16f);
#pragma unroll
    for (int q = 0; q < 16; q++) {
        const int r = q >> 1;  // compile-time per unrolled q
        if ((q & 1) == 0) h[r][c]       = xg[(size_t)(b0 + r) * EMB + c] * rden[r];
        else              h[r][EMB + c] = xgp[(size_t)(b0 + r) * EMB + c];
    }
    __syncthreads();
    float acc[8] = {0.f, 0.f, 0.f, 0.f, 0.f, 0.f, 0.f, 0.f};
    for (int k = 0; k < 2 * EMB; k++) {
        float wv = Wtr[(size_t)k * EMB + c];
#pragma unroll
        for (int r = 0; r < 8; r++) acc[r] += h[r][k] * wv;
    }
#pragma unroll
    for (int r = 0; r < 8; r++) {
        float v = acc[r] + bt[c];
        v = (v >= 0.f) ? v : SLOPE * v;
        out[(size_t)(b0 + r) * EMB + c] = v + xgp[(size_t)(b0 + r) * EMB + c];
    }
}

extern "C" void kernel_launch(void* const* d_in, const int* in_sizes, int n_in,
                              void* d_out, int out_size, void* d_ws, size_t ws_size,
                              hipStream_t stream) {
    const float* xgp  = (const float*)d_in[0];
    const float* x    = (const float*)d_in[1];
    const int*   bind = (const int*)d_in[2];
    const float* Wm   = (const float*)d_in[3];
    const float* bm   = (const float*)d_in[4];
    const float* Wf   = (const float*)d_in[5];
    const float* bf   = (const float*)d_in[6];
    const float* Wtr  = (const float*)d_in[7];
    const float* bt   = (const float*)d_in[8];
    float* out = (float*)d_out;

    char* ws = (char*)d_ws;
    unsigned short* Wt    = (unsigned short*)ws;                  // 256*256 bf16 = 131072 B
    float*          denom = (float*)(ws + 131072);                // 512 f32
    float*          xg    = (float*)(ws + 131072 + 2048);         // 512*256 f32

    hipLaunchKernelGGL(k_prep,  dim3(258),          dim3(256), 0, stream, Wf, Wt, denom, xg);
    hipLaunchKernelGGL(k_fused, dim3(NROWS / 64),   dim3(256), 0, stream, x, Wt, Wm, bm, bf, bind, denom, xg);
    hipLaunchKernelGGL(k_out,   dim3(NB / 8),       dim3(256), 0, stream, xg, denom, xgp, Wtr, bt, out);
}

// Round 3
// 254.867 us; speedup vs baseline: 22.1604x; 2.5962x over previous
//
#include <hip/hip_runtime.h>
#include <cstdint>
#include <cstddef>

#define NROWS 262144
#define EMB 256
#define NB 512
#define SLOPE 0.01f

typedef __attribute__((ext_vector_type(8))) short short8;
typedef __attribute__((ext_vector_type(4))) float f32x4;

__device__ __forceinline__ unsigned short f2bf(float f) {
    unsigned u = __float_as_uint(f);
    u += 0x7FFFu + ((u >> 16) & 1u);
    return (unsigned short)(u >> 16);
}

// ---------- prep: transpose W_feat -> bf16 Wt[col][k], zero denom & xg ----------
__global__ __launch_bounds__(256) void k_prep(const float* __restrict__ Wf,
                                              unsigned short* __restrict__ Wt,
                                              float* __restrict__ denom,
                                              float* __restrict__ xg) {
    int b = blockIdx.x, t = threadIdx.x;
    if (b < 256) {
        float v = Wf[(size_t)b * EMB + t];   // W_feat[k=b][col=t]
        Wt[(size_t)t * EMB + b] = f2bf(v);   // Wt[col][k]
        xg[(size_t)b * 512 + t] = 0.f;
        xg[(size_t)b * 512 + 256 + t] = 0.f;
    } else if (b == 256) {
        denom[t] = 0.f;
    } else {
        denom[256 + t] = 0.f;
    }
}

// ---------- fused: gate + exp + bf16 MFMA feat GEMM + weighted segment reduce ----------
// 256 threads (4 waves). Tile: 64 rows x 256 cols. Wave w: wr=w>>1 (32-row half),
// wc=w&1 (128-col half). A-frags and B-frags loaded straight into registers
// (no LDS staging, no main-loop barriers). A loads are 16-deep per m-half to
// keep HBM saturated; B prefetched one K-step ahead from L2-resident Wt.
__global__ __launch_bounds__(256, 2) void k_fused(const float* __restrict__ x,
                                                  const unsigned short* __restrict__ Wt,
                                                  const float* __restrict__ wm,
                                                  const float* __restrict__ bfeat,
                                                  const int* __restrict__ bind,
                                                  float* __restrict__ denom,
                                                  float* __restrict__ xg) {
    __shared__ float wm_s[256];
    __shared__ float w_s[64];
    __shared__ int   seg_s[64];
    __shared__ int   segid_s[4];
    __shared__ int   uni_s[4];

    const int t    = threadIdx.x;
    const int r0   = blockIdx.x * 64;
    const int lane = t & 63;
    const int w    = t >> 6;
    const int wr   = w >> 1, wc = w & 1;
    const int fr   = lane & 15;      // fragment row (A) / col (B)
    const int fg   = lane >> 4;      // k-group 0..3
    const int fk   = fg * 8;

    wm_s[t] = wm[t];
    if (t < 64) seg_s[t] = bind[r0 + t];
    __syncthreads();
    if (t < 4) {
        int s0 = seg_s[t * 16], ok = 1;
#pragma unroll
        for (int i = 1; i < 16; i++) ok &= (seg_s[t * 16 + i] == s0);
        segid_s[t] = s0;
        uni_s[t]   = ok;
    }

    // ---- A phase: 32 rows x 256 k straight into registers; gate partials fp32 ----
    short8 a_bf[2][8];
    float  gp[2];
#pragma unroll
    for (int m = 0; m < 2; m++) {
        const float* xb = x + (size_t)(r0 + wr * 32 + m * 16 + fr) * EMB + fk;
        float4 lo[8], hi[8];
#pragma unroll
        for (int kq = 0; kq < 8; kq++) {
            lo[kq] = *reinterpret_cast<const float4*>(xb + kq * 32);
            hi[kq] = *reinterpret_cast<const float4*>(xb + kq * 32 + 4);
        }
        float g = 0.f;
#pragma unroll
        for (int kq = 0; kq < 8; kq++) {
            const float4 wa = *reinterpret_cast<const float4*>(&wm_s[kq * 32 + fk]);
            const float4 wb = *reinterpret_cast<const float4*>(&wm_s[kq * 32 + fk + 4]);
            g += lo[kq].x * wa.x + lo[kq].y * wa.y + lo[kq].z * wa.z + lo[kq].w * wa.w
               + hi[kq].x * wb.x + hi[kq].y * wb.y + hi[kq].z * wb.z + hi[kq].w * wb.w;
            short8 s;
            s[0] = (short)f2bf(lo[kq].x); s[1] = (short)f2bf(lo[kq].y);
            s[2] = (short)f2bf(lo[kq].z); s[3] = (short)f2bf(lo[kq].w);
            s[4] = (short)f2bf(hi[kq].x); s[5] = (short)f2bf(hi[kq].y);
            s[6] = (short)f2bf(hi[kq].z); s[7] = (short)f2bf(hi[kq].w);
            a_bf[m][kq] = s;
        }
        gp[m] = g;
    }

    // gate: reduce k-groups (lanes l, l+16, l+32, l+48 share a row)
#pragma unroll
    for (int m = 0; m < 2; m++) {
        gp[m] += __shfl_xor(gp[m], 16, 64);
        gp[m] += __shfl_xor(gp[m], 32, 64);
    }
    // exp(bm) cancels exactly between numerator and denominator -> dropped
    if (wc == 0 && lane < 16) {
#pragma unroll
        for (int m = 0; m < 2; m++) w_s[wr * 32 + m * 16 + lane] = expf(gp[m]);
    }

    // ---- B kt=0 prefetch (L2-resident) ----
    const unsigned short* wb0 = Wt + (size_t)(wc * 128 + fr) * EMB + fk;
    short8 b_cur[8], b_nxt[8];
#pragma unroll
    for (int n = 0; n < 8; n++)
        b_cur[n] = *reinterpret_cast<const short8*>(wb0 + (size_t)n * 16 * EMB);

    f32x4 acc[2][8];
#pragma unroll
    for (int m = 0; m < 2; m++)
#pragma unroll
        for (int n = 0; n < 8; n++) acc[m][n] = (f32x4){0.f, 0.f, 0.f, 0.f};

    __syncthreads();   // w_s, uni_s, segid_s ready

    // denom: <=4 atomics/block typical, overlaps with MFMA phase of other waves
    if (t < 4) {
        if (uni_s[t]) {
            float s = 0.f;
#pragma unroll
            for (int i = 0; i < 16; i++) s += w_s[t * 16 + i];
            atomicAdd(&denom[segid_s[t]], s);
        } else {
            for (int i = 0; i < 16; i++)
                atomicAdd(&denom[seg_s[t * 16 + i]], w_s[t * 16 + i]);
        }
    }

    // ---- main loop: 8 K-steps, B prefetched one step ahead, no barriers ----
#pragma unroll
    for (int ks = 0; ks < 8; ks++) {
        if (ks < 7) {
#pragma unroll
            for (int n = 0; n < 8; n++)
                b_nxt[n] = *reinterpret_cast<const short8*>(
                    wb0 + (size_t)n * 16 * EMB + (ks + 1) * 32);
        }
#pragma unroll
        for (int n = 0; n < 8; n++) {
            acc[0][n] = __builtin_amdgcn_mfma_f32_16x16x32_bf16(a_bf[0][ks], b_cur[n], acc[0][n], 0, 0, 0);
            acc[1][n] = __builtin_amdgcn_mfma_f32_16x16x32_bf16(a_bf[1][ks], b_cur[n], acc[1][n], 0, 0, 0);
        }
#pragma unroll
        for (int n = 0; n < 8; n++) b_cur[n] = b_nxt[n];
    }

    // ---- epilogue: bias -> leaky -> *e -> segmented reduce -> atomics ----
#pragma unroll
    for (int m = 0; m < 2; m++) {
        const int g    = wr * 2 + m;
        const int uni  = uni_s[g];
        const int sid  = segid_s[g];
        const int rowb = wr * 32 + m * 16;
#pragma unroll
        for (int n = 0; n < 8; n++) {
            const int col = wc * 128 + n * 16 + fr;
            const float bia = bfeat[col];
            float vr[4];
#pragma unroll
            for (int r = 0; r < 4; r++) {
                const int row = rowb + fg * 4 + r;
                float v = acc[m][n][r] + bia;
                v = (v >= 0.f) ? v : SLOPE * v;
                vr[r] = v * w_s[row];
            }
            if (uni) {
                float s = vr[0] + vr[1] + vr[2] + vr[3];
                s += __shfl_xor(s, 16, 64);
                s += __shfl_xor(s, 32, 64);
                if (fg == 0) atomicAdd(&xg[(size_t)sid * EMB + col], s);
            } else {
#pragma unroll
                for (int r = 0; r < 4; r++) {
                    const int row = rowb + fg * 4 + r;
                    atomicAdd(&xg[(size_t)seg_s[row] * EMB + col], vr[r]);
                }
            }
        }
    }
}

// ---------- out = leaky_relu([xg/denom, xg_prev] @ W_t + b_t) + xg_prev ----------
__global__ __launch_bounds__(256) void k_out(const float* __restrict__ xg,
                                             const float* __restrict__ denom,
                                             const float* __restrict__ xgp,
                                             const float* __restrict__ Wtr,
                                             const float* __restrict__ bt,
                                             float* __restrict__ out) {
    __shared__ float h[8][512];
    const int c  = threadIdx.x;
    const int b0 = blockIdx.x * 8;
    float rden[8];
#pragma unroll
    for (int r = 0; r < 8; r++) rden[r] = 1.f / fmaxf(denom[b0 + r], 1e-16f);
#pragma unroll
    for (int q = 0; q < 16; q++) {
        const int r = q >> 1;
        if ((q & 1) == 0) h[r][c]       = xg[(size_t)(b0 + r) * EMB + c] * rden[r];
        else              h[r][EMB + c] = xgp[(size_t)(b0 + r) * EMB + c];
    }
    __syncthreads();
    float acc[8] = {0.f, 0.f, 0.f, 0.f, 0.f, 0.f, 0.f, 0.f};
    for (int k = 0; k < 2 * EMB; k++) {
        float wv = Wtr[(size_t)k * EMB + c];
#pragma unroll
        for (int r = 0; r < 8; r++) acc[r] += h[r][k] * wv;
    }
#pragma unroll
    for (int r = 0; r < 8; r++) {
        float v = acc[r] + bt[c];
        v = (v >= 0.f) ? v : SLOPE * v;
        out[(size_t)(b0 + r) * EMB + c] = v + xgp[(size_t)(b0 + r) * EMB + c];
    }
}

extern "C" void kernel_launch(void* const* d_in, const int* in_sizes, int n_in,
                              void* d_out, int out_size, void* d_ws, size_t ws_size,
                              hipStream_t stream) {
    const float* xgp  = (const float*)d_in[0];
    const float* x    = (const float*)d_in[1];
    const int*   bind = (const int*)d_in[2];
    const float* Wm   = (const float*)d_in[3];
    const float* Wf   = (const float*)d_in[5];
    const float* bf   = (const float*)d_in[6];
    const float* Wtr  = (const float*)d_in[7];
    const float* bt   = (const float*)d_in[8];
    float* out = (float*)d_out;

    char* ws = (char*)d_ws;
    unsigned short* Wt    = (unsigned short*)ws;                  // 256*256 bf16 = 131072 B
    float*          denom = (float*)(ws + 131072);                // 512 f32
    float*          xg    = (float*)(ws + 131072 + 2048);         // 512*256 f32

    hipLaunchKernelGGL(k_prep,  dim3(258),        dim3(256), 0, stream, Wf, Wt, denom, xg);
    hipLaunchKernelGGL(k_fused, dim3(NROWS / 64), dim3(256), 0, stream, x, Wt, Wm, bf, bind, denom, xg);
    hipLaunchKernelGGL(k_out,   dim3(NB / 8),     dim3(256), 0, stream, xg, denom, xgp, Wtr, bt, out);
}